// Round 1
// baseline (1454.419 us; speedup 1.0000x reference)
//
#include <hip/hip_runtime.h>
#include <math.h>

#define H_DIM 2048
#define I_DIM 5632
#define E_NUM 8
#define T_NUM 32
#define GROUP 16
#define ISPLIT 4
#define IRANGE (I_DIM / ISPLIT)   // 1408
#define SWIGLU_SCALE 1.702f

// ---------------- Router: logits -> softmax -> top-2 -> sparse combine ----------------
__global__ __launch_bounds__(256) void router_kernel(
    const float* __restrict__ x, const float* __restrict__ rw,
    float* __restrict__ combine) {
  const int t = blockIdx.x;
  __shared__ float xs[H_DIM];
  __shared__ float red[4];
  __shared__ float logits[E_NUM];
  for (int h = threadIdx.x; h < H_DIM; h += 256) xs[h] = x[t * H_DIM + h];
  __syncthreads();
  const int lane = threadIdx.x & 63;
  const int wave = threadIdx.x >> 6;
  for (int e = 0; e < E_NUM; ++e) {
    float p = 0.f;
    for (int h = threadIdx.x; h < H_DIM; h += 256) p += xs[h] * rw[e * H_DIM + h];
    for (int off = 32; off; off >>= 1) p += __shfl_down(p, off);
    if (lane == 0) red[wave] = p;
    __syncthreads();
    if (threadIdx.x == 0) logits[e] = red[0] + red[1] + red[2] + red[3];
    __syncthreads();
  }
  if (threadIdx.x == 0) {
    float m = logits[0];
    for (int e = 1; e < E_NUM; ++e) m = fmaxf(m, logits[e]);
    float a[E_NUM]; float s = 0.f;
    for (int e = 0; e < E_NUM; ++e) { a[e] = __expf(logits[e] - m); s += a[e]; }
    const float inv = 1.f / s;
    for (int e = 0; e < E_NUM; ++e) a[e] *= inv;
    int i1 = -1, i2 = -1; float v1 = -1.f, v2 = -1.f;
    for (int e = 0; e < E_NUM; ++e) {
      if (a[e] > v1)      { v2 = v1; i2 = i1; v1 = a[e]; i1 = e; }
      else if (a[e] > v2) { v2 = a[e]; i2 = e; }
    }
    for (int e = 0; e < E_NUM; ++e)
      combine[t * E_NUM + e] = (e == i1) ? v1 : ((e == i2) ? v2 : 0.f);
  }
}

// ---------------- Compaction: per-expert token lists ----------------
__global__ void compact_kernel(const float* __restrict__ combine,
                               int* __restrict__ cnt, int* __restrict__ tok,
                               float* __restrict__ scale) {
  const int e = threadIdx.x;
  if (e >= E_NUM) return;
  int c = 0;
  for (int t = 0; t < T_NUM; ++t) {
    const float v = combine[t * E_NUM + e];
    if (v > 0.f) { tok[e * T_NUM + c] = t; scale[e * T_NUM + c] = v; ++c; }
  }
  cnt[e] = c;
  for (int s = c; s < T_NUM; ++s) { tok[e * T_NUM + s] = 0; scale[e * T_NUM + s] = 0.f; }
}

// ---------------- Gate/Up + swiglu: inter[e][slot][i] = swiglu(gate)*up*combine ----------------
__global__ __launch_bounds__(256) void gateup_kernel(
    const float* __restrict__ x, const float* __restrict__ wg,
    const float* __restrict__ wu, const int* __restrict__ cnt,
    const int* __restrict__ tok, const float* __restrict__ scale,
    float* __restrict__ inter) {
  const int e = blockIdx.x;        // 8 -> one expert per XCD (x-major round-robin)
  const int chunk = blockIdx.y;    // 22 chunks of 256 i's
  const int tg = blockIdx.z;       // 2 token-groups of 16
  const int n0 = tg * GROUP;
  const int c = cnt[e];
  if (n0 >= c) return;
  const int i = chunk * 256 + threadIdx.x;

  int tj[GROUP]; float sc[GROUP];
#pragma unroll
  for (int j = 0; j < GROUP; ++j) {
    tj[j] = __builtin_amdgcn_readfirstlane(tok[e * T_NUM + n0 + j]);
    sc[j] = scale[e * T_NUM + n0 + j];
  }
  float accg[GROUP], accu[GROUP];
#pragma unroll
  for (int j = 0; j < GROUP; ++j) { accg[j] = 0.f; accu[j] = 0.f; }

  const float* wgp = wg + (size_t)e * H_DIM * I_DIM + i;
  const float* wup = wu + (size_t)e * H_DIM * I_DIM + i;
  for (int h = 0; h < H_DIM; ++h) {
    const float g = wgp[(size_t)h * I_DIM];
    const float u = wup[(size_t)h * I_DIM];
#pragma unroll
    for (int j = 0; j < GROUP; ++j) {
      const float xv = x[tj[j] * H_DIM + h];   // wave-uniform -> s_load
      accg[j] = fmaf(g, xv, accg[j]);
      accu[j] = fmaf(u, xv, accu[j]);
    }
  }

  float* ip = inter + ((size_t)e * T_NUM + n0) * I_DIM + i;
#pragma unroll
  for (int j = 0; j < GROUP; ++j) {
    const float gg = accg[j];
    const float sig = 1.f / (1.f + __expf(-SWIGLU_SCALE * gg));
    ip[(size_t)j * I_DIM] = gg * sig * accu[j] * sc[j];
  }
}

// ---------------- Down-proj: out[t][h] += sum_i inter[e][slot][i] * wd[e][i][h] ----------------
__global__ __launch_bounds__(256) void down_kernel(
    const float* __restrict__ wd, const float* __restrict__ inter,
    const int* __restrict__ cnt, const int* __restrict__ tok,
    float* __restrict__ out) {
  const int e = blockIdx.x;        // 8 -> XCD
  const int hc = blockIdx.y;       // 8 chunks of 256 h
  const int z = blockIdx.z;        // 8 = isplit(4) x tg(2)
  const int isp = z & 3;
  const int tg = z >> 2;
  const int n0 = tg * GROUP;
  const int c = cnt[e];
  if (n0 >= c) return;
  const int h = hc * 256 + threadIdx.x;

  int tj[GROUP];
#pragma unroll
  for (int j = 0; j < GROUP; ++j)
    tj[j] = __builtin_amdgcn_readfirstlane(tok[e * T_NUM + n0 + j]);

  float acc[GROUP];
#pragma unroll
  for (int j = 0; j < GROUP; ++j) acc[j] = 0.f;

  const float* wdp = wd + (size_t)e * I_DIM * H_DIM + (size_t)isp * IRANGE * H_DIM + h;
  const float* itp = inter + ((size_t)e * T_NUM + n0) * I_DIM + isp * IRANGE;
  for (int ii = 0; ii < IRANGE; ++ii) {
    const float w = wdp[(size_t)ii * H_DIM];
#pragma unroll
    for (int j = 0; j < GROUP; ++j)
      acc[j] = fmaf(w, itp[(size_t)j * I_DIM + ii], acc[j]);  // itp uniform -> s_load
  }

  const int nt = min(GROUP, c - n0);
  for (int j = 0; j < nt; ++j)
    atomicAdd(&out[tj[j] * H_DIM + h], acc[j]);
}

// ---------------- Launch ----------------
extern "C" void kernel_launch(void* const* d_in, const int* in_sizes, int n_in,
                              void* d_out, int out_size, void* d_ws, size_t ws_size,
                              hipStream_t stream) {
  const float* x  = (const float*)d_in[0];   // [32,1,2048]
  const float* rw = (const float*)d_in[1];   // [8,2048]
  const float* wg = (const float*)d_in[2];   // [8,2048,5632]
  const float* wu = (const float*)d_in[3];   // [8,2048,5632]
  const float* wd = (const float*)d_in[4];   // [8,5632,2048]
  float* out = (float*)d_out;                // [32,1,2048] f32

  float* ws      = (float*)d_ws;
  float* combine = ws;                        // 256 f32
  int*   cnt     = (int*)(ws + 256);          // 8
  int*   tok     = (int*)(ws + 264);          // 256
  float* scale   = ws + 520;                  // 256
  float* inter   = ws + 1024;                 // 8*32*5632 f32 = 5.77 MB

  hipMemsetAsync(d_out, 0, (size_t)out_size * sizeof(float), stream);
  router_kernel<<<T_NUM, 256, 0, stream>>>(x, rw, combine);
  compact_kernel<<<1, 64, 0, stream>>>(combine, cnt, tok, scale);
  gateup_kernel<<<dim3(E_NUM, I_DIM / 256, 2), 256, 0, stream>>>(x, wg, wu, cnt, tok, scale, inter);
  down_kernel<<<dim3(E_NUM, H_DIM / 256, ISPLIT * 2), 256, 0, stream>>>(wd, inter, cnt, tok, out);
}

// Round 2
// 268.585 us; speedup vs baseline: 5.4151x; 5.4151x over previous
//
#include <hip/hip_runtime.h>
#include <math.h>

#define H_DIM 2048
#define I_DIM 5632
#define E_NUM 8
#define T_NUM 32
#define P_NUM 64              // total (token,expert) pairs = T*K exactly
#define GROUP 16
#define HS 8                  // h-splits in gateup
#define HCH (H_DIM / HS)      // 256
#define IS 16                 // i-splits in down
#define ICH (I_DIM / IS)      // 352
#define SWIGLU_SCALE 1.702f

// ---------------- Router: logits -> softmax -> top-2 -> sparse combine ----------------
__global__ __launch_bounds__(256) void router_kernel(
    const float* __restrict__ x, const float* __restrict__ rw,
    float* __restrict__ combine) {
  const int t = blockIdx.x;
  __shared__ float xs[H_DIM];
  __shared__ float red[4];
  __shared__ float logits[E_NUM];
  for (int h = threadIdx.x; h < H_DIM; h += 256) xs[h] = x[t * H_DIM + h];
  __syncthreads();
  const int lane = threadIdx.x & 63;
  const int wave = threadIdx.x >> 6;
  for (int e = 0; e < E_NUM; ++e) {
    float p = 0.f;
    for (int h = threadIdx.x; h < H_DIM; h += 256) p += xs[h] * rw[e * H_DIM + h];
    for (int off = 32; off; off >>= 1) p += __shfl_down(p, off);
    if (lane == 0) red[wave] = p;
    __syncthreads();
    if (threadIdx.x == 0) logits[e] = red[0] + red[1] + red[2] + red[3];
    __syncthreads();
  }
  if (threadIdx.x == 0) {
    float m = logits[0];
    for (int e = 1; e < E_NUM; ++e) m = fmaxf(m, logits[e]);
    float a[E_NUM]; float s = 0.f;
    for (int e = 0; e < E_NUM; ++e) { a[e] = __expf(logits[e] - m); s += a[e]; }
    const float inv = 1.f / s;
    for (int e = 0; e < E_NUM; ++e) a[e] *= inv;
    int i1 = -1, i2 = -1; float v1 = -1.f, v2 = -1.f;
    for (int e = 0; e < E_NUM; ++e) {
      if (a[e] > v1)      { v2 = v1; i2 = i1; v1 = a[e]; i1 = e; }
      else if (a[e] > v2) { v2 = a[e]; i2 = e; }
    }
    for (int e = 0; e < E_NUM; ++e)
      combine[t * E_NUM + e] = (e == i1) ? v1 : ((e == i2) ? v2 : 0.f);
  }
}

// ---------------- Compaction: global expert-sorted pair list (64 pairs) ----------------
__global__ void compact_kernel(const float* __restrict__ combine,
                               int* __restrict__ cnt, int* __restrict__ start,
                               int* __restrict__ ptok, float* __restrict__ pscale) {
  __shared__ unsigned char flag[T_NUM][E_NUM];
  __shared__ int scnt[E_NUM], sstart[E_NUM];
  const int tid = threadIdx.x;
  {
    const int t = tid >> 3, e = tid & 7;   // 256 = 32*8
    flag[t][e] = combine[t * E_NUM + e] > 0.f;
  }
  __syncthreads();
  if (tid < E_NUM) {
    int c = 0;
    for (int t = 0; t < T_NUM; ++t) c += flag[t][tid];
    scnt[tid] = c;
  }
  __syncthreads();
  if (tid == 0) {
    int s = 0;
    for (int e = 0; e < E_NUM; ++e) { sstart[e] = s; s += scnt[e]; }
  }
  __syncthreads();
  if (tid < E_NUM) {
    cnt[tid] = scnt[tid];
    start[tid] = sstart[tid];
    int p = sstart[tid];
    for (int t = 0; t < T_NUM; ++t)
      if (flag[t][tid]) { ptok[p] = t; pscale[p] = combine[t * E_NUM + tid]; ++p; }
  }
  if (tid >= P_NUM && tid < P_NUM + 32) { ptok[tid] = 0; pscale[tid] = 0.f; }
}

// ---------------- Gate/Up partial GEMM (h-split by HS) ----------------
// EPI==0: write partials to pg[hs][pair][i].  EPI==1: atomicAdd into pg[pair][i].
template<int EPI>
__global__ __launch_bounds__(256) void gateup_kernel(
    const float* __restrict__ x, const float* __restrict__ wg,
    const float* __restrict__ wu, const int* __restrict__ cnt,
    const int* __restrict__ start, const int* __restrict__ ptok,
    float* __restrict__ pg, float* __restrict__ pu) {
  const int e  = blockIdx.x;
  const int ic = blockIdx.y;              // 11 chunks of 512 i
  const int hs = blockIdx.z & (HS - 1);   // 8 h-chunks of 256
  const int tg = blockIdx.z >> 3;         // 2 token groups of 16
  const int c  = cnt[e];
  const int n0 = tg * GROUP;
  if (n0 >= c) return;
  const int nt = min(GROUP, c - n0);
  const int p0 = start[e] + n0;
  const int tid = threadIdx.x;
  const int h0 = hs * HCH;

  __shared__ float xs[GROUP][HCH];        // 16 KB
#pragma unroll
  for (int j = 0; j < GROUP; ++j)
    xs[j][tid] = (j < nt) ? x[ptok[p0 + j] * H_DIM + h0 + tid] : 0.f;
  __syncthreads();

  const int i2 = ic * 512 + tid * 2;
  const float* wgp = wg + ((size_t)e * H_DIM + h0) * I_DIM + i2;
  const float* wup = wu + ((size_t)e * H_DIM + h0) * I_DIM + i2;

  float ag[GROUP][2], au[GROUP][2];
#pragma unroll
  for (int j = 0; j < GROUP; ++j) { ag[j][0] = ag[j][1] = au[j][0] = au[j][1] = 0.f; }

#pragma unroll 4
  for (int hh = 0; hh < HCH; ++hh) {
    const float2 g = *(const float2*)(wgp + (size_t)hh * I_DIM);
    const float2 u = *(const float2*)(wup + (size_t)hh * I_DIM);
#pragma unroll
    for (int j = 0; j < GROUP; ++j) {
      const float xv = xs[j][hh];
      ag[j][0] = fmaf(g.x, xv, ag[j][0]);
      ag[j][1] = fmaf(g.y, xv, ag[j][1]);
      au[j][0] = fmaf(u.x, xv, au[j][0]);
      au[j][1] = fmaf(u.y, xv, au[j][1]);
    }
  }

  if (EPI == 0) {
    float* pgp = pg + (size_t)hs * P_NUM * I_DIM;
    float* pup = pu + (size_t)hs * P_NUM * I_DIM;
#pragma unroll
    for (int j = 0; j < GROUP; ++j) if (j < nt) {
      *(float2*)(pgp + (size_t)(p0 + j) * I_DIM + i2) = make_float2(ag[j][0], ag[j][1]);
      *(float2*)(pup + (size_t)(p0 + j) * I_DIM + i2) = make_float2(au[j][0], au[j][1]);
    }
  } else {
#pragma unroll
    for (int j = 0; j < GROUP; ++j) if (j < nt) {
      const size_t o = (size_t)(p0 + j) * I_DIM + i2;
      atomicAdd(&pg[o],     ag[j][0]);
      atomicAdd(&pg[o + 1], ag[j][1]);
      atomicAdd(&pu[o],     au[j][0]);
      atomicAdd(&pu[o + 1], au[j][1]);
    }
  }
}

// ---------------- Reduce partials + swiglu + combine-scale -> inter[pair][i] ----------------
template<int EPI>
__global__ __launch_bounds__(256) void swiglu_kernel(
    const float* __restrict__ pg, const float* __restrict__ pu,
    const float* __restrict__ pscale, float* __restrict__ inter) {
  const int p = blockIdx.x;
  const int i = blockIdx.y * 256 + threadIdx.x;
  const size_t off = (size_t)p * I_DIM + i;
  float g, u;
  if (EPI == 0) {
    g = 0.f; u = 0.f;
#pragma unroll
    for (int hs = 0; hs < HS; ++hs) {
      g += pg[(size_t)hs * P_NUM * I_DIM + off];
      u += pu[(size_t)hs * P_NUM * I_DIM + off];
    }
  } else {
    g = pg[off]; u = pu[off];
  }
  const float s = pscale[p];
  const float sig = 1.f / (1.f + __expf(-SWIGLU_SCALE * g));
  inter[off] = g * sig * u * s;
}

// ---------------- Down-proj: out[t][h] += sum_i inter[pair][i] * wd[e][i][h] ----------------
__global__ __launch_bounds__(256) void down_kernel(
    const float* __restrict__ wd, const float* __restrict__ inter,
    const int* __restrict__ cnt, const int* __restrict__ start,
    const int* __restrict__ ptok, float* __restrict__ out) {
  const int e  = blockIdx.x;
  const int hc = blockIdx.y;              // 4 chunks of 512 h
  const int is = blockIdx.z & (IS - 1);   // 16 chunks of 352 i
  const int tg = blockIdx.z >> 4;         // 2 token groups
  const int c  = cnt[e];
  const int n0 = tg * GROUP;
  if (n0 >= c) return;
  const int nt = min(GROUP, c - n0);
  const int p0 = start[e] + n0;
  const int tid = threadIdx.x;
  const int i0 = is * ICH;

  __shared__ float ils[GROUP][ICH];       // 22528 B
  for (int idx = tid; idx < GROUP * ICH; idx += 256) {
    const int j = idx / ICH, ii = idx - j * ICH;
    ils[j][ii] = (j < nt) ? inter[(size_t)(p0 + j) * I_DIM + i0 + ii] : 0.f;
  }
  __syncthreads();

  const int h2 = hc * 512 + tid * 2;
  const float* wdp = wd + ((size_t)e * I_DIM + i0) * H_DIM + h2;

  float acc[GROUP][2];
#pragma unroll
  for (int j = 0; j < GROUP; ++j) { acc[j][0] = acc[j][1] = 0.f; }

#pragma unroll 4
  for (int ii = 0; ii < ICH; ++ii) {
    const float2 w = *(const float2*)(wdp + (size_t)ii * H_DIM);
#pragma unroll
    for (int j = 0; j < GROUP; ++j) {
      const float iv = ils[j][ii];
      acc[j][0] = fmaf(w.x, iv, acc[j][0]);
      acc[j][1] = fmaf(w.y, iv, acc[j][1]);
    }
  }

#pragma unroll
  for (int j = 0; j < GROUP; ++j) if (j < nt) {
    const int t = ptok[p0 + j];
    atomicAdd(&out[t * H_DIM + h2],     acc[j][0]);
    atomicAdd(&out[t * H_DIM + h2 + 1], acc[j][1]);
  }
}

// ---------------- Launch ----------------
extern "C" void kernel_launch(void* const* d_in, const int* in_sizes, int n_in,
                              void* d_out, int out_size, void* d_ws, size_t ws_size,
                              hipStream_t stream) {
  const float* x  = (const float*)d_in[0];   // [32,1,2048]
  const float* rw = (const float*)d_in[1];   // [8,2048]
  const float* wg = (const float*)d_in[2];   // [8,2048,5632]
  const float* wu = (const float*)d_in[3];   // [8,2048,5632]
  const float* wd = (const float*)d_in[4];   // [8,5632,2048]
  float* out = (float*)d_out;                // [32,1,2048] f32

  float* ws      = (float*)d_ws;
  float* combine = ws;                        // 256 f32
  int*   cnt     = (int*)(ws + 256);          // 8
  int*   start   = (int*)(ws + 264);          // 8
  int*   ptok    = (int*)(ws + 272);          // 96 (padded)
  float* pscale  = ws + 368;                  // 96 (padded)
  float* inter   = ws + 512;                  // 64*5632 = 1.44 MB
  float* pg      = inter + (size_t)P_NUM * I_DIM;

  // partial path: pg/pu are [HS][64][5632] each (11.5 MB each)
  const size_t partial_elems = (size_t)HS * P_NUM * I_DIM;
  const size_t need_partial  = (512 + (size_t)P_NUM * I_DIM + 2 * partial_elems) * sizeof(float);
  const bool   use_partial   = ws_size >= need_partial;
  float* pu = pg + (use_partial ? partial_elems : (size_t)P_NUM * I_DIM);

  hipMemsetAsync(d_out, 0, (size_t)out_size * sizeof(float), stream);
  router_kernel<<<T_NUM, 256, 0, stream>>>(x, rw, combine);
  compact_kernel<<<1, 256, 0, stream>>>(combine, cnt, start, ptok, pscale);

  if (use_partial) {
    gateup_kernel<0><<<dim3(E_NUM, I_DIM / 512, HS * 2), 256, 0, stream>>>(
        x, wg, wu, cnt, start, ptok, pg, pu);
    swiglu_kernel<0><<<dim3(P_NUM, I_DIM / 256), 256, 0, stream>>>(pg, pu, pscale, inter);
  } else {
    hipMemsetAsync(pg, 0, 2 * (size_t)P_NUM * I_DIM * sizeof(float), stream);
    gateup_kernel<1><<<dim3(E_NUM, I_DIM / 512, HS * 2), 256, 0, stream>>>(
        x, wg, wu, cnt, start, ptok, pg, pu);
    swiglu_kernel<1><<<dim3(P_NUM, I_DIM / 256), 256, 0, stream>>>(pg, pu, pscale, inter);
  }

  down_kernel<<<dim3(E_NUM, H_DIM / 512, IS * 2), 256, 0, stream>>>(
      wd, inter, cnt, start, ptok, out);
}